// Round 10
// baseline (332.527 us; speedup 1.0000x reference)
//
#include <hip/hip_runtime.h>
#include <math.h>

// B=8, Cin=64, Cout=32, H=W=8 (P=64), RH=32, E=512.
// kP:    fused weight transposes (8 blocks) + X1W precompute (72 blocks)
// kF:    forward, LDS-staged weights + packed masks + y    (8 x 1024)
// kHopG: wide hopfield -> g = 2(y-yq), layout [b][m][o]    (512 x 64)
// kJ:    4 waves per (b,i,type), ci-quarter K-split with   (1024 x 256)
//        LDS-atomic partial reduction, 29 KB LDS.
//        NOTE: no min-waves launch-bounds arg — round 9's (256,4) forced a
//        64-VGPR cap -> scratch spills (FETCH 8.9MB, WRITE 19.5MB, VALU 28%).
// kQ:    routed gather (butterfly) + hopfield -> out       (512 x 64)

// ---- ws layout ----
constexpr int OFF_MBIT = 0;                        // ints: 8*3*64 uint2
constexpr int OFF_N    = 3072;                     // floats [b][s][rh][p]
constexpr int OFF_G    = OFF_N    + 32768;         // 8*2048 [b][m][o]
constexpr int OFF_Y    = OFF_G    + 16384;         // 8*2048 [b][tok][c]
constexpr int OFF_X1W  = OFF_Y    + 16384;         // 8*64*9*64 [b][i][k][co]
constexpr int OFF_WSUM = OFF_X1W  + 294912;        // 576 pad 640 [k][co]
constexpr int OFF_W1RT = OFF_WSUM + 640;           // 2*9*64*32 [s][k][ci][co32]
constexpr int OFF_W2RT = OFF_W1RT + 36864;         // 2*32*64 [s][ci32][co64]
constexpr int OFF_WC2T = OFF_W2RT + 4096;          // 64*32 [ci64][o32]
constexpr int OFF_W1T  = OFF_WC2T + 2048;          // (unused hole, keeps offsets)
constexpr int OFF_T    = OFF_W1T  + 36864;         // 8*64*64*32 [b][i][m][o]
constexpr int OFF_IDX  = OFF_T    + 1048576;       // 512 ints

// ---------------- register-tiled conv GEMM primitives ----------------
__device__ __forceinline__ void conv3x3_tile(
    const float* __restrict__ Wg, const int COdim, const int co0,
    const float* __restrict__ Bp, const int ciBase, const int ciN,
    const int lr, const int lc, float acc[4][8])
{
#pragma unroll
  for (int k = 0; k < 9; k++) {
    const int dy = k / 3 - 1, dx = k % 3 - 1;
    const float* wrow = Wg + (k * 64 + ciBase) * COdim + co0 + lc * 4;
    const float* brow = Bp + ciBase * 80 + (1 + lr + dy) * 8;
#pragma unroll 4
    for (int ci = 0; ci < ciN; ci++) {
      float4 wv = *(const float4*)(wrow + ci * COdim);
      float4 b0 = *(const float4*)(brow + ci * 80);
      float4 b1 = *(const float4*)(brow + ci * 80 + 4);
      float bb[8] = {b0.x, b0.y, b0.z, b0.w, b1.x, b1.y, b1.z, b1.w};
      float wj[4] = {wv.x, wv.y, wv.z, wv.w};
#pragma unroll
      for (int j = 0; j < 4; j++)
#pragma unroll
        for (int px = 0; px < 8; px++) {
          const int sx = px + dx;
          if (sx >= 0 && sx <= 7) acc[j][px] = fmaf(wj[j], bb[sx], acc[j][px]);
        }
    }
  }
}

__device__ __forceinline__ void conv1x1_tile(
    const float* __restrict__ Wg, const int COdim, const int co0,
    const float* __restrict__ Bp, const int ciBase, const int ciN,
    const int lr, const int lc, float acc[4][8])
{
  const float* wbase = Wg + ciBase * COdim + co0 + lc * 4;
  const float* bbase = Bp + ciBase * 80 + (1 + lr) * 8;
#pragma unroll 4
  for (int ci = 0; ci < ciN; ci++) {
    float4 wv = *(const float4*)(wbase + ci * COdim);
    float4 b0 = *(const float4*)(bbase + ci * 80);
    float4 b1 = *(const float4*)(bbase + ci * 80 + 4);
    float bb[8] = {b0.x, b0.y, b0.z, b0.w, b1.x, b1.y, b1.z, b1.w};
    float wj[4] = {wv.x, wv.y, wv.z, wv.w};
#pragma unroll
    for (int j = 0; j < 4; j++)
#pragma unroll
      for (int px = 0; px < 8; px++)
        acc[j][px] = fmaf(wj[j], bb[px], acc[j][px]);
  }
}

__device__ __forceinline__ void store_tile(float* dst, int lr, int lc,
                                           const float acc[4][8])
{
#pragma unroll
  for (int j = 0; j < 4; j++) {
    *(float4*)(dst + (lc * 4 + j) * 64 + lr * 8) =
        make_float4(acc[j][0], acc[j][1], acc[j][2], acc[j][3]);
    *(float4*)(dst + (lc * 4 + j) * 64 + lr * 8 + 4) =
        make_float4(acc[j][4], acc[j][5], acc[j][6], acc[j][7]);
  }
}

// ---------------- kP: fused kW (blocks 72..79) + kX (blocks 0..71) ----------------
__global__ __launch_bounds__(256) void kP(
    const float* __restrict__ x, const float* __restrict__ w1,
    const float* __restrict__ r0w1, const float* __restrict__ r0w2,
    const float* __restrict__ r1w1, const float* __restrict__ r1w2,
    const float* __restrict__ w2, float* ws)
{
  const int bk = blockIdx.x;
  const int t = threadIdx.x;
  __shared__ __align__(16) float Xp[5120];
  __shared__ __align__(16) float Pq[8192];
  __shared__ __align__(16) float Wk[4096];

  if (bk >= 72) {
    const int t0 = (bk - 72) * 256 + t;
    const int stride = 8 * 256;
    for (int e = t0; e < 18432; e += stride) {
      int co = e & 31, ci = (e >> 5) & 63, k = e >> 11;
      ws[OFF_W1RT + e]         = r0w1[(co * 64 + ci) * 9 + k];
      ws[OFF_W1RT + 18432 + e] = r1w1[(co * 64 + ci) * 9 + k];
    }
    for (int e = t0; e < 2048; e += stride) {
      int co = e & 63, ci = e >> 6;
      ws[OFF_W2RT + e]        = r0w2[co * 32 + ci];
      ws[OFF_W2RT + 2048 + e] = r1w2[co * 32 + ci];
      int o = e & 31, c2 = e >> 5;
      ws[OFF_WC2T + e] = w2[o * 64 + c2];
    }
    for (int e = t0; e < 576; e += stride) {
      int k = e >> 6, co = e & 63;
      float a = 0.f;
      for (int ci = 0; ci < 64; ci++) a += w1[(co * 64 + ci) * 9 + k];
      ws[OFF_WSUM + e] = a;
    }
    return;
  }

  const int b = bk / 9, k = bk % 9;
  const int w = t >> 6, lane = t & 63;
  const int lr = lane >> 3, lc = lane & 7;
  for (int e = t; e < 4096; e += 256) {
    int ci = e >> 6, p = e & 63;
    Xp[ci * 80 + 8 + p] = x[b * 4096 + e];
  }
  for (int e = t; e < 4096; e += 256) {
    int ci = e >> 6, co = e & 63;
    Wk[e] = w1[(co * 64 + ci) * 9 + k];   // Wk[ci][co]
  }
  __syncthreads();
  float acc[4][8];
#pragma unroll
  for (int j = 0; j < 4; j++)
#pragma unroll
    for (int px = 0; px < 8; px++) acc[j][px] = 0.f;
  const int cohalf = w & 1, ks = w >> 1;
  conv1x1_tile(Wk, 64, cohalf * 32, Xp, ks * 32, 32, lr, lc, acc);
  store_tile(Pq + ks * 4096 + cohalf * 2048, lr, lc, acc);
  __syncthreads();
  for (int e = t; e < 4096; e += 256) {
    int co = e & 63, i = e >> 6;
    int pin = (co >> 5) * 2048 + (co & 31) * 64 + i;
    ws[OFF_X1W + ((b * 64 + i) * 9 + k) * 64 + co] = Pq[pin] + Pq[4096 + pin];
  }
}

// ---------------- kF: forward with LDS-staged weights ----------------
__global__ __launch_bounds__(1024) void kF(
    const float* __restrict__ b1, const float* __restrict__ b2,
    const float* __restrict__ wsc, float* ws)
{
  const int b = blockIdx.x, t = threadIdx.x;
  const int w = t >> 6, lane = t & 63, lr = lane >> 3, lc = lane & 7;
  __shared__ __align__(16) float Apad[5120];
  __shared__ __align__(16) float Yl[4096];
  __shared__ __align__(16) float Pq[18432];
  __shared__ __align__(16) float Hpad[2560];
  __shared__ __align__(16) float Wsm[2048];
  __shared__ __align__(16) float Wsm2[2048];
  unsigned int* wsi = (unsigned int*)ws;

  if (t < 1024) {
    int ci = t >> 4, r9 = (t >> 3) & 1, c = t & 7;
    Apad[ci * 80 + r9 * 72 + c] = 0.f;
  }
  if (t < 512) {
    int ci = t >> 4, r9 = (t >> 3) & 1, c = t & 7;
    Hpad[ci * 80 + r9 * 72 + c] = 0.f;
  }

  {
    const int co4 = t & 15, p = t >> 4;
    const int py = p >> 3, px = p & 7;
    float4 a = ((const float4*)b1)[co4];
#pragma unroll
    for (int k = 0; k < 9; k++) {
      int dy = k / 3 - 1, dx = k % 3 - 1;
      int qy = py + dy, qx = px + dx;
      if ((unsigned)qy < 8u && (unsigned)qx < 8u) {
        int ik = qy * 8 + qx;
        float4 v = *(const float4*)(wsc + OFF_X1W + ((b * 64 + ik) * 9 + k) * 64 + co4 * 4);
        a.x += v.x; a.y += v.y; a.z += v.z; a.w += v.w;
      }
    }
    float av[4] = {a.x, a.y, a.z, a.w};
#pragma unroll
    for (int j = 0; j < 4; j++) {
      int co = co4 * 4 + j;
      Yl[co * 64 + p] = av[j];
      Apad[co * 80 + 8 + p] = fmaxf(av[j], 0.f);
    }
  }
  __syncthreads();
  if (t < 64) {
    unsigned int lo = 0, hi = 0;
#pragma unroll
    for (int ci = 0; ci < 32; ci++) lo |= (Yl[ci * 64 + t] > 0.f ? 1u : 0u) << ci;
#pragma unroll
    for (int ci = 0; ci < 32; ci++) hi |= (Yl[(32 + ci) * 64 + t] > 0.f ? 1u : 0u) << ci;
    wsi[OFF_MBIT + ((b * 3 + 0) * 64 + t) * 2]     = lo;
    wsi[OFF_MBIT + ((b * 3 + 0) * 64 + t) * 2 + 1] = hi;
  }

  float acc[4][8];
  for (int s = 0; s < 2; s++) {
    {
      const float2* src = (const float2*)(wsc + OFF_W1RT + s * 18432);
      float2* dst = (float2*)Pq;
#pragma unroll
      for (int z = 0; z < 9; z++) dst[z * 1024 + t] = src[z * 1024 + t];
    }
    __syncthreads();
    if (w < 8) {
#pragma unroll
      for (int j = 0; j < 4; j++)
#pragma unroll
        for (int px = 0; px < 8; px++) acc[j][px] = 0.f;
      conv3x3_tile(Pq, 32, 0, Apad, w * 8, 8, lr, lc, acc);
    } else {
      int tt = t - 512;
#pragma unroll
      for (int z = 0; z < 4; z++) Wsm[z * 512 + tt] = wsc[OFF_W2RT + s * 2048 + z * 512 + tt];
      if (s == 1) {
#pragma unroll
        for (int z = 0; z < 4; z++) Wsm2[z * 512 + tt] = wsc[OFF_WC2T + z * 512 + tt];
      }
    }
    __syncthreads();
    if (w < 8) store_tile(Pq + w * 2048, lr, lc, acc);
    __syncthreads();
    for (int e = t; e < 2048; e += 1024) {
      int rh = e >> 6, p = e & 63;
      float hv = 0.f;
#pragma unroll
      for (int ks = 0; ks < 8; ks++) hv += Pq[ks * 2048 + e];
      ws[OFF_N + (b * 2 + s) * 2048 + e] = hv > 0.f ? 1.f : 0.f;
      Hpad[rh * 80 + 8 + p] = fmaxf(hv, 0.f);
    }
    __syncthreads();
    if (w < 8) {
#pragma unroll
      for (int j = 0; j < 4; j++)
#pragma unroll
        for (int px = 0; px < 8; px++) acc[j][px] = 0.f;
      const int cohalf = w & 1, ks = w >> 1;
      conv1x1_tile(Wsm, 64, cohalf * 32, Hpad, ks * 8, 8, lr, lc, acc);
      store_tile(Pq + ks * 4096 + cohalf * 2048, lr, lc, acc);
    }
    __syncthreads();
    for (int e = t; e < 4096; e += 1024) {
      int co = e >> 6, p = e & 63;
      int pin = (co >> 5) * 2048 + (co & 31) * 64 + p;
      float d = 0.f;
#pragma unroll
      for (int ks = 0; ks < 4; ks++) d += Pq[ks * 4096 + pin];
      float ny = Yl[e] + d;
      Yl[e] = ny;
      Apad[co * 80 + 8 + p] = fmaxf(ny, 0.f);
    }
    __syncthreads();
    if (t < 64) {
      unsigned int lo = 0, hi = 0;
#pragma unroll
      for (int ci = 0; ci < 32; ci++) lo |= (Yl[ci * 64 + t] > 0.f ? 1u : 0u) << ci;
#pragma unroll
      for (int ci = 0; ci < 32; ci++) hi |= (Yl[(32 + ci) * 64 + t] > 0.f ? 1u : 0u) << ci;
      wsi[OFF_MBIT + ((b * 3 + 1 + s) * 64 + t) * 2]     = lo;
      wsi[OFF_MBIT + ((b * 3 + 1 + s) * 64 + t) * 2 + 1] = hi;
    }
  }

  if (w < 8) {
#pragma unroll
    for (int j = 0; j < 4; j++)
#pragma unroll
      for (int px = 0; px < 8; px++) acc[j][px] = 0.f;
    conv1x1_tile(Wsm2, 32, 0, Apad, w * 8, 8, lr, lc, acc);
    store_tile(Pq + w * 2048, lr, lc, acc);
  }
  __syncthreads();
  for (int e = t; e < 2048; e += 1024) {
    int o = e >> 6, p = e & 63;
    float yv = b2[o];
#pragma unroll
    for (int ks = 0; ks < 8; ks++) yv += Pq[ks * 2048 + e];
    ws[OFF_Y + b * 2048 + p * 32 + o] = yv;  // [b][tok][c]
  }
}

// ---------------- kHopG: wide hopfield -> g, one wave per (b,tok) ----------------
__global__ __launch_bounds__(64) void kHopG(const float* __restrict__ wsc,
                                            const float* __restrict__ pat,
                                            float* __restrict__ ws)
{
  const int b = blockIdx.x >> 6, tok = blockIdx.x & 63;
  const int lane = threadIdx.x;
  const float* yp = wsc + OFF_Y + b * 2048 + tok * 32;
  float4 ya[8];
#pragma unroll
  for (int r = 0; r < 8; r++) ya[r] = ((const float4*)yp)[r];

  float l[8];
#pragma unroll
  for (int j = 0; j < 8; j++) {
    const float4* pp = (const float4*)(pat + (j * 64 + lane) * 32);
    float lj = 0.f;
#pragma unroll
    for (int c4 = 0; c4 < 8; c4++) {
      float4 pv = pp[c4];
      lj = fmaf(ya[c4].x, pv.x, lj);
      lj = fmaf(ya[c4].y, pv.y, lj);
      lj = fmaf(ya[c4].z, pv.z, lj);
      lj = fmaf(ya[c4].w, pv.w, lj);
    }
    l[j] = lj * 0.17677669529663687f;
  }
  float mx = -1e30f;
#pragma unroll
  for (int j = 0; j < 8; j++) mx = fmaxf(mx, l[j]);
#pragma unroll
  for (int off = 32; off > 0; off >>= 1) mx = fmaxf(mx, __shfl_xor(mx, off, 64));
  float num[8]; float dsum = 0.f;
#pragma unroll
  for (int j = 0; j < 8; j++) { num[j] = __expf(l[j] - mx); dsum += num[j]; }
#pragma unroll
  for (int off = 32; off > 0; off >>= 1) dsum += __shfl_xor(dsum, off, 64);

  float q[32];
#pragma unroll
  for (int c = 0; c < 32; c++) q[c] = 0.f;
#pragma unroll
  for (int j = 0; j < 8; j++) {
    const float4* pp = (const float4*)(pat + (j * 64 + lane) * 32);
    float nj = num[j];
#pragma unroll
    for (int c4 = 0; c4 < 8; c4++) {
      float4 pv = pp[c4];
      q[c4 * 4 + 0] = fmaf(nj, pv.x, q[c4 * 4 + 0]);
      q[c4 * 4 + 1] = fmaf(nj, pv.y, q[c4 * 4 + 1]);
      q[c4 * 4 + 2] = fmaf(nj, pv.z, q[c4 * 4 + 2]);
      q[c4 * 4 + 3] = fmaf(nj, pv.w, q[c4 * 4 + 3]);
    }
  }
#pragma unroll
  for (int off = 32; off > 0; off >>= 1) {
#pragma unroll
    for (int c = 0; c < 32; c++) q[c] += __shfl_xor(q[c], off, 64);
  }
  if (lane == 0) {
    float invd = 1.f / dsum;
    float yy[32];
#pragma unroll
    for (int c4 = 0; c4 < 8; c4++) {
      yy[c4 * 4 + 0] = ya[c4].x; yy[c4 * 4 + 1] = ya[c4].y;
      yy[c4 * 4 + 2] = ya[c4].z; yy[c4 * 4 + 3] = ya[c4].w;
    }
    float* gp = ws + OFF_G + b * 2048 + tok * 32;
#pragma unroll
    for (int c4 = 0; c4 < 8; c4++)
      *(float4*)(gp + c4 * 4) = make_float4(
          2.f * (yy[c4 * 4 + 0] - q[c4 * 4 + 0] * invd),
          2.f * (yy[c4 * 4 + 1] - q[c4 * 4 + 1] * invd),
          2.f * (yy[c4 * 4 + 2] - q[c4 * 4 + 2] * invd),
          2.f * (yy[c4 * 4 + 3] - q[c4 * 4 + 3] * invd));
  }
}

// ---------------- kJ: 4 waves per (b,i,type), ci-quarter + LDS atomics ----------------
__global__ __launch_bounds__(256) void kJ(const float* __restrict__ wsc, float* ws)
{
  const int bid = blockIdx.x;
  const int type = bid & 1, i = (bid >> 1) & 63, b = bid >> 7;
  const int t = threadIdx.x;
  const int w = t >> 6, p = t & 63;        // wave owns ci-quarter [16w,16w+16)
  const int lr = p >> 3, lc = p & 7;
  const int py = p >> 3, px = p & 7, iy = i >> 3, ix = i & 7;
  __shared__ __align__(16) float Up[5120];   // padded im2col; flat (stride-68) overlay for dT/final
  __shared__ __align__(16) float Vf[2176];   // V accumulator [32][68]
  const unsigned int* wsi = (const unsigned int*)wsc;

  float Tq[16];  // channels [16w, 16w+16) at pixel p
  {
    int kh = iy - py + 1, kw = ix - px + 1;
    bool v0 = (unsigned)kh < 3u && (unsigned)kw < 3u;
    int kidx = v0 ? kh * 3 + kw : 0;
    const float4* s4 = (const float4*)(type
        ? (wsc + OFF_X1W + ((b * 64 + i) * 9 + kidx) * 64)
        : (wsc + OFF_WSUM + kidx * 64)) + w * 4;
#pragma unroll
    for (int c4 = 0; c4 < 4; c4++) {
      float4 tv = s4[c4];
      Tq[c4 * 4 + 0] = v0 ? tv.x : 0.f;
      Tq[c4 * 4 + 1] = v0 ? tv.y : 0.f;
      Tq[c4 * 4 + 2] = v0 ? tv.z : 0.f;
      Tq[c4 * 4 + 3] = v0 ? tv.w : 0.f;
    }
  }

  float acc[4][8];
  for (int s = 0; s < 2; s++) {
    if (s) __syncthreads();                 // prior-stage flat reads done before rebuild
    // zero own Vf rows [8w, 8w+8)
    for (int e = p; e < 544; e += 64) Vf[w * 544 + e] = 0.f;
    // masked padded U build (own quarter) + re-zero own pad rows
    {
      unsigned int mword = wsi[OFF_MBIT + ((b * 3 + s) * 64 + p) * 2 + (w >> 1)];
      unsigned int mq = (mword >> ((w & 1) * 16)) & 0xFFFFu;
#pragma unroll
      for (int c = 0; c < 16; c++)
        Up[(16 * w + c) * 80 + 8 + p] = ((mq >> c) & 1u) ? Tq[c] : 0.f;
#pragma unroll
      for (int z = 0; z < 4; z++) {
        int e = z * 64 + p;                 // 0..255
        int ci = 16 * w + (e >> 4);
        Up[ci * 80 + ((e >> 3) & 1) * 72 + (e & 7)] = 0.f;
      }
    }
    __syncthreads();                        // Vf zeroed (and U quarters built)
    // conv3x3 partial over own ci quarter -> all 32 co
#pragma unroll
    for (int j = 0; j < 4; j++)
#pragma unroll
      for (int pq = 0; pq < 8; pq++) acc[j][pq] = 0.f;
    conv3x3_tile(wsc + OFF_W1RT + s * 18432, 32, 0, Up, w * 16, 16, lr, lc, acc);
    // fold N mask in distributively and atomically accumulate V
    {
      const float* Np = wsc + OFF_N + (b * 2 + s) * 2048;
#pragma unroll
      for (int j = 0; j < 4; j++) {
        int rh = lc * 4 + j;
        float4 n0 = *(const float4*)(Np + rh * 64 + lr * 8);
        float4 n1 = *(const float4*)(Np + rh * 64 + lr * 8 + 4);
        float* vrow = &Vf[rh * 68 + lr * 8];
        atomicAdd(vrow + 0, acc[j][0] * n0.x);
        atomicAdd(vrow + 1, acc[j][1] * n0.y);
        atomicAdd(vrow + 2, acc[j][2] * n0.z);
        atomicAdd(vrow + 3, acc[j][3] * n0.w);
        atomicAdd(vrow + 4, acc[j][4] * n1.x);
        atomicAdd(vrow + 5, acc[j][5] * n1.y);
        atomicAdd(vrow + 6, acc[j][6] * n1.z);
        atomicAdd(vrow + 7, acc[j][7] * n1.w);
      }
    }
    __syncthreads();                        // Vf complete
    // dT own co-quarter [16w,16w+16), K=32 from Vf (stride 68)
    {
      float a2[2][8];
#pragma unroll
      for (int j = 0; j < 2; j++)
#pragma unroll
        for (int pq = 0; pq < 8; pq++) a2[j][pq] = 0.f;
      const float* wbase = wsc + OFF_W2RT + s * 2048 + 16 * w + lc * 2;
      const float* bbase = Vf + lr * 8;
#pragma unroll 4
      for (int ci = 0; ci < 32; ci++) {
        float2 wv = *(const float2*)(wbase + ci * 64);
        float4 b0 = *(const float4*)(bbase + ci * 68);
        float4 b1 = *(const float4*)(bbase + ci * 68 + 4);
        float bb[8] = {b0.x, b0.y, b0.z, b0.w, b1.x, b1.y, b1.z, b1.w};
#pragma unroll
        for (int pq = 0; pq < 8; pq++) {
          a2[0][pq] = fmaf(wv.x, bb[pq], a2[0][pq]);
          a2[1][pq] = fmaf(wv.y, bb[pq], a2[1][pq]);
        }
      }
      // store to own flat rows (stride 68) in Up, then gather own column
#pragma unroll
      for (int j = 0; j < 2; j++) {
        int co = 16 * w + lc * 2 + j;
        *(float4*)(&Up[co * 68 + lr * 8]) =
            make_float4(a2[j][0], a2[j][1], a2[j][2], a2[j][3]);
        *(float4*)(&Up[co * 68 + lr * 8 + 4]) =
            make_float4(a2[j][4], a2[j][5], a2[j][6], a2[j][7]);
      }
#pragma unroll
      for (int c = 0; c < 16; c++) Tq[c] += Up[(16 * w + c) * 68 + p];
    }
  }
  __syncthreads();
  // final 1x1 with M2 mask: masked flat build (own quarter, stride 68)
  {
    unsigned int mword = wsi[OFF_MBIT + ((b * 3 + 2) * 64 + p) * 2 + (w >> 1)];
    unsigned int mq = (mword >> ((w & 1) * 16)) & 0xFFFFu;
#pragma unroll
    for (int c = 0; c < 16; c++)
      Up[(16 * w + c) * 68 + p] = ((mq >> c) & 1u) ? Tq[c] : 0.f;
  }
  __syncthreads();
  // out co-octet per wave: co = 8w + lc, K=64
  {
    float a1[8];
#pragma unroll
    for (int pq = 0; pq < 8; pq++) a1[pq] = 0.f;
    const float* wc = wsc + OFF_WC2T + 8 * w + lc;
    const float* bbase = Up + lr * 8;
#pragma unroll 4
    for (int ci = 0; ci < 64; ci++) {
      float wv = wc[ci * 32];
      float4 b0 = *(const float4*)(bbase + ci * 68);
      float4 b1 = *(const float4*)(bbase + ci * 68 + 4);
      a1[0] = fmaf(wv, b0.x, a1[0]);
      a1[1] = fmaf(wv, b0.y, a1[1]);
      a1[2] = fmaf(wv, b0.z, a1[2]);
      a1[3] = fmaf(wv, b0.w, a1[3]);
      a1[4] = fmaf(wv, b1.x, a1[4]);
      a1[5] = fmaf(wv, b1.y, a1[5]);
      a1[6] = fmaf(wv, b1.z, a1[6]);
      a1[7] = fmaf(wv, b1.w, a1[7]);
    }
    *(float4*)(&Vf[(8 * w + lc) * 68 + lr * 8]) = make_float4(a1[0], a1[1], a1[2], a1[3]);
    *(float4*)(&Vf[(8 * w + lc) * 68 + lr * 8 + 4]) = make_float4(a1[4], a1[5], a1[6], a1[7]);
  }
  __syncthreads();

  if (type == 0) {
    if (w == 0) {
      // e[m=p] = sum_o g[b][p][o] * out[o][p]
      const float* gp = wsc + OFF_G + b * 2048 + p * 32;
      float e = 0.f;
#pragma unroll
      for (int o4 = 0; o4 < 8; o4++) {
        float4 gv = *(const float4*)(gp + o4 * 4);
        int o = o4 * 4;
        e = fmaf(gv.x, Vf[(o + 0) * 68 + p], e);
        e = fmaf(gv.y, Vf[(o + 1) * 68 + p], e);
        e = fmaf(gv.z, Vf[(o + 2) * 68 + p], e);
        e = fmaf(gv.w, Vf[(o + 3) * 68 + p], e);
      }
      float bv = e; int bi = p;
#pragma unroll
      for (int off = 1; off < 64; off <<= 1) {
        float ov = __shfl_xor(bv, off, 64);
        int oi = __shfl_xor(bi, off, 64);
        if (ov < bv || (ov == bv && oi < bi)) { bv = ov; bi = oi; }
      }
      if (p == 0) ((int*)(ws + OFF_IDX))[b * 64 + i] = bi;
    }
  } else {
    // T[b][i][m][o], 512 float4 over 256 threads
    float* Tp = ws + OFF_T + (b * 64 + i) * 2048;
#pragma unroll
    for (int z = 0; z < 2; z++) {
      int e4 = z * 256 + t;                 // 0..511
      int m = e4 >> 3, o0 = (e4 & 7) * 4;
      *(float4*)(Tp + e4 * 4) = make_float4(
          Vf[(o0 + 0) * 68 + m], Vf[(o0 + 1) * 68 + m],
          Vf[(o0 + 2) * 68 + m], Vf[(o0 + 3) * 68 + m]);
    }
  }
}

// ---------------- kQ: routed gather + hopfield -> out ----------------
__global__ __launch_bounds__(64) void kQ(const float* __restrict__ wsc,
                                         const float* __restrict__ pat,
                                         float* __restrict__ outp)
{
  const int b = blockIdx.x >> 6, tok = blockIdx.x & 63;
  const int lane = threadIdx.x;
  const int sidx = ((const int*)(wsc + OFF_IDX))[b * 64 + lane];
  const bool sel = (sidx == tok);
  float ym[32];
  const float4* Tp = (const float4*)(wsc + OFF_T + ((b * 64 + lane) * 64 + tok) * 32);
#pragma unroll
  for (int c4 = 0; c4 < 8; c4++) {
    float4 tv = Tp[c4];
    ym[c4 * 4 + 0] = sel ? tv.x : 0.f;
    ym[c4 * 4 + 1] = sel ? tv.y : 0.f;
    ym[c4 * 4 + 2] = sel ? tv.z : 0.f;
    ym[c4 * 4 + 3] = sel ? tv.w : 0.f;
  }
#pragma unroll
  for (int off = 1; off < 64; off <<= 1) {
#pragma unroll
    for (int c = 0; c < 32; c++) ym[c] += __shfl_xor(ym[c], off, 64);
  }
  float l[8];
#pragma unroll
  for (int j = 0; j < 8; j++) {
    const float4* pp = (const float4*)(pat + (j * 64 + lane) * 32);
    float lj = 0.f;
#pragma unroll
    for (int c4 = 0; c4 < 8; c4++) {
      float4 pv = pp[c4];
      lj = fmaf(ym[c4 * 4 + 0], pv.x, lj);
      lj = fmaf(ym[c4 * 4 + 1], pv.y, lj);
      lj = fmaf(ym[c4 * 4 + 2], pv.z, lj);
      lj = fmaf(ym[c4 * 4 + 3], pv.w, lj);
    }
    l[j] = lj * 0.17677669529663687f;
  }
  float mx = -1e30f;
#pragma unroll
  for (int j = 0; j < 8; j++) mx = fmaxf(mx, l[j]);
#pragma unroll
  for (int off = 32; off > 0; off >>= 1) mx = fmaxf(mx, __shfl_xor(mx, off, 64));
  float num[8]; float dsum = 0.f;
#pragma unroll
  for (int j = 0; j < 8; j++) { num[j] = __expf(l[j] - mx); dsum += num[j]; }
#pragma unroll
  for (int off = 32; off > 0; off >>= 1) dsum += __shfl_xor(dsum, off, 64);
  float q[32];
#pragma unroll
  for (int c = 0; c < 32; c++) q[c] = 0.f;
#pragma unroll
  for (int j = 0; j < 8; j++) {
    const float4* pp = (const float4*)(pat + (j * 64 + lane) * 32);
    float nj = num[j];
#pragma unroll
    for (int c4 = 0; c4 < 8; c4++) {
      float4 pv = pp[c4];
      q[c4 * 4 + 0] = fmaf(nj, pv.x, q[c4 * 4 + 0]);
      q[c4 * 4 + 1] = fmaf(nj, pv.y, q[c4 * 4 + 1]);
      q[c4 * 4 + 2] = fmaf(nj, pv.z, q[c4 * 4 + 2]);
      q[c4 * 4 + 3] = fmaf(nj, pv.w, q[c4 * 4 + 3]);
    }
  }
#pragma unroll
  for (int off = 32; off > 0; off >>= 1) {
#pragma unroll
    for (int c = 0; c < 32; c++) q[c] += __shfl_xor(q[c], off, 64);
  }
  if (lane == 0) {
    float invd = 1.f / dsum;
#pragma unroll
    for (int c = 0; c < 32; c++)
      outp[b * 2048 + c * 64 + tok] = q[c] * invd;
  }
}

extern "C" void kernel_launch(void* const* d_in, const int* in_sizes, int n_in,
                              void* d_out, int out_size, void* d_ws, size_t ws_size,
                              hipStream_t stream) {
  (void)in_sizes; (void)n_in; (void)out_size; (void)ws_size;
  const float* x    = (const float*)d_in[0];
  const float* w1   = (const float*)d_in[1];
  const float* b1   = (const float*)d_in[2];
  const float* r0w1 = (const float*)d_in[3];
  const float* r0w2 = (const float*)d_in[4];
  const float* r1w1 = (const float*)d_in[5];
  const float* r1w2 = (const float*)d_in[6];
  const float* w2   = (const float*)d_in[7];
  const float* b2   = (const float*)d_in[8];
  const float* pat  = (const float*)d_in[9];
  float* ws  = (float*)d_ws;
  float* out = (float*)d_out;

  kP<<<80, 256, 0, stream>>>(x, w1, r0w1, r0w2, r1w1, r1w2, w2, ws);
  kF<<<8, 1024, 0, stream>>>(b1, b2, ws, ws);
  kHopG<<<512, 64, 0, stream>>>(ws, pat, ws);
  kJ<<<1024, 256, 0, stream>>>(ws, ws);
  kQ<<<512, 64, 0, stream>>>(ws, pat, out);
}

// Round 11
// 229.008 us; speedup vs baseline: 1.4520x; 1.4520x over previous
//
#include <hip/hip_runtime.h>
#include <math.h>

// B=8, Cin=64, Cout=32, H=W=8 (P=64), RH=32, E=512.
// kP:    fused weight transposes (8 blocks) + X1W precompute (72 blocks)
// kF:    forward, LDS-staged weights + packed masks + y    (8 x 1024)
// kHopG: wide hopfield -> g = 2(y-yq), layout [b][m][o]    (512 x 64)
// kJ:    PAIRED: both tangent types of (b,i) in one block, (512 x 256)
//        each pair = round-8's proven 2-wave K-split on its own LDS region.
//        512 blocks -> 2 blocks/CU x 8 waves = 16 waves/CU (4/SIMD).
// kQ:    routed gather (butterfly) + hopfield -> out       (512 x 64)

// ---- ws layout ----
constexpr int OFF_MBIT = 0;                        // ints: 8*3*64 uint2
constexpr int OFF_N    = 3072;                     // floats [b][s][rh][p]
constexpr int OFF_G    = OFF_N    + 32768;         // 8*2048 [b][m][o]
constexpr int OFF_Y    = OFF_G    + 16384;         // 8*2048 [b][tok][c]
constexpr int OFF_X1W  = OFF_Y    + 16384;         // 8*64*9*64 [b][i][k][co]
constexpr int OFF_WSUM = OFF_X1W  + 294912;        // 576 pad 640 [k][co]
constexpr int OFF_W1RT = OFF_WSUM + 640;           // 2*9*64*32 [s][k][ci][co32]
constexpr int OFF_W2RT = OFF_W1RT + 36864;         // 2*32*64 [s][ci32][co64]
constexpr int OFF_WC2T = OFF_W2RT + 4096;          // 64*32 [ci64][o32]
constexpr int OFF_W1T  = OFF_WC2T + 2048;          // (unused hole, keeps offsets)
constexpr int OFF_T    = OFF_W1T  + 36864;         // 8*64*64*32 [b][i][m][o]
constexpr int OFF_IDX  = OFF_T    + 1048576;       // 512 ints

// ---------------- register-tiled conv GEMM primitives ----------------
__device__ __forceinline__ void conv3x3_tile(
    const float* __restrict__ Wg, const int COdim, const int co0,
    const float* __restrict__ Bp, const int ciBase, const int ciN,
    const int lr, const int lc, float acc[4][8])
{
#pragma unroll
  for (int k = 0; k < 9; k++) {
    const int dy = k / 3 - 1, dx = k % 3 - 1;
    const float* wrow = Wg + (k * 64 + ciBase) * COdim + co0 + lc * 4;
    const float* brow = Bp + ciBase * 80 + (1 + lr + dy) * 8;
#pragma unroll 4
    for (int ci = 0; ci < ciN; ci++) {
      float4 wv = *(const float4*)(wrow + ci * COdim);
      float4 b0 = *(const float4*)(brow + ci * 80);
      float4 b1 = *(const float4*)(brow + ci * 80 + 4);
      float bb[8] = {b0.x, b0.y, b0.z, b0.w, b1.x, b1.y, b1.z, b1.w};
      float wj[4] = {wv.x, wv.y, wv.z, wv.w};
#pragma unroll
      for (int j = 0; j < 4; j++)
#pragma unroll
        for (int px = 0; px < 8; px++) {
          const int sx = px + dx;
          if (sx >= 0 && sx <= 7) acc[j][px] = fmaf(wj[j], bb[sx], acc[j][px]);
        }
    }
  }
}

__device__ __forceinline__ void conv1x1_tile(
    const float* __restrict__ Wg, const int COdim, const int co0,
    const float* __restrict__ Bp, const int ciBase, const int ciN,
    const int lr, const int lc, float acc[4][8])
{
  const float* wbase = Wg + ciBase * COdim + co0 + lc * 4;
  const float* bbase = Bp + ciBase * 80 + (1 + lr) * 8;
#pragma unroll 4
  for (int ci = 0; ci < ciN; ci++) {
    float4 wv = *(const float4*)(wbase + ci * COdim);
    float4 b0 = *(const float4*)(bbase + ci * 80);
    float4 b1 = *(const float4*)(bbase + ci * 80 + 4);
    float bb[8] = {b0.x, b0.y, b0.z, b0.w, b1.x, b1.y, b1.z, b1.w};
    float wj[4] = {wv.x, wv.y, wv.z, wv.w};
#pragma unroll
    for (int j = 0; j < 4; j++)
#pragma unroll
      for (int px = 0; px < 8; px++)
        acc[j][px] = fmaf(wj[j], bb[px], acc[j][px]);
  }
}

// flat (no-halo) B layout Bf[ci][64]
__device__ __forceinline__ void conv1x1_flat(
    const float* __restrict__ Wg, const int COdim, const int co0,
    const float* __restrict__ Bf, const int ciBase, const int ciN,
    const int lr, const int lc, float acc[4][8])
{
  const float* wbase = Wg + ciBase * COdim + co0 + lc * 4;
  const float* bbase = Bf + ciBase * 64 + lr * 8;
#pragma unroll 4
  for (int ci = 0; ci < ciN; ci++) {
    float4 wv = *(const float4*)(wbase + ci * COdim);
    float4 b0 = *(const float4*)(bbase + ci * 64);
    float4 b1 = *(const float4*)(bbase + ci * 64 + 4);
    float bb[8] = {b0.x, b0.y, b0.z, b0.w, b1.x, b1.y, b1.z, b1.w};
    float wj[4] = {wv.x, wv.y, wv.z, wv.w};
#pragma unroll
    for (int j = 0; j < 4; j++)
#pragma unroll
      for (int px = 0; px < 8; px++)
        acc[j][px] = fmaf(wj[j], bb[px], acc[j][px]);
  }
}

__device__ __forceinline__ void store_tile(float* dst, int lr, int lc,
                                           const float acc[4][8])
{
#pragma unroll
  for (int j = 0; j < 4; j++) {
    *(float4*)(dst + (lc * 4 + j) * 64 + lr * 8) =
        make_float4(acc[j][0], acc[j][1], acc[j][2], acc[j][3]);
    *(float4*)(dst + (lc * 4 + j) * 64 + lr * 8 + 4) =
        make_float4(acc[j][4], acc[j][5], acc[j][6], acc[j][7]);
  }
}

// ---------------- kP: fused kW (blocks 72..79) + kX (blocks 0..71) ----------------
__global__ __launch_bounds__(256) void kP(
    const float* __restrict__ x, const float* __restrict__ w1,
    const float* __restrict__ r0w1, const float* __restrict__ r0w2,
    const float* __restrict__ r1w1, const float* __restrict__ r1w2,
    const float* __restrict__ w2, float* ws)
{
  const int bk = blockIdx.x;
  const int t = threadIdx.x;
  __shared__ __align__(16) float Xp[5120];
  __shared__ __align__(16) float Pq[8192];
  __shared__ __align__(16) float Wk[4096];

  if (bk >= 72) {
    const int t0 = (bk - 72) * 256 + t;
    const int stride = 8 * 256;
    for (int e = t0; e < 18432; e += stride) {
      int co = e & 31, ci = (e >> 5) & 63, k = e >> 11;
      ws[OFF_W1RT + e]         = r0w1[(co * 64 + ci) * 9 + k];
      ws[OFF_W1RT + 18432 + e] = r1w1[(co * 64 + ci) * 9 + k];
    }
    for (int e = t0; e < 2048; e += stride) {
      int co = e & 63, ci = e >> 6;
      ws[OFF_W2RT + e]        = r0w2[co * 32 + ci];
      ws[OFF_W2RT + 2048 + e] = r1w2[co * 32 + ci];
      int o = e & 31, c2 = e >> 5;
      ws[OFF_WC2T + e] = w2[o * 64 + c2];
    }
    for (int e = t0; e < 576; e += stride) {
      int k = e >> 6, co = e & 63;
      float a = 0.f;
      for (int ci = 0; ci < 64; ci++) a += w1[(co * 64 + ci) * 9 + k];
      ws[OFF_WSUM + e] = a;
    }
    return;
  }

  const int b = bk / 9, k = bk % 9;
  const int w = t >> 6, lane = t & 63;
  const int lr = lane >> 3, lc = lane & 7;
  for (int e = t; e < 4096; e += 256) {
    int ci = e >> 6, p = e & 63;
    Xp[ci * 80 + 8 + p] = x[b * 4096 + e];
  }
  for (int e = t; e < 4096; e += 256) {
    int ci = e >> 6, co = e & 63;
    Wk[e] = w1[(co * 64 + ci) * 9 + k];   // Wk[ci][co]
  }
  __syncthreads();
  float acc[4][8];
#pragma unroll
  for (int j = 0; j < 4; j++)
#pragma unroll
    for (int px = 0; px < 8; px++) acc[j][px] = 0.f;
  const int cohalf = w & 1, ks = w >> 1;
  conv1x1_tile(Wk, 64, cohalf * 32, Xp, ks * 32, 32, lr, lc, acc);
  store_tile(Pq + ks * 4096 + cohalf * 2048, lr, lc, acc);
  __syncthreads();
  for (int e = t; e < 4096; e += 256) {
    int co = e & 63, i = e >> 6;
    int pin = (co >> 5) * 2048 + (co & 31) * 64 + i;
    ws[OFF_X1W + ((b * 64 + i) * 9 + k) * 64 + co] = Pq[pin] + Pq[4096 + pin];
  }
}

// ---------------- kF: forward with LDS-staged weights ----------------
__global__ __launch_bounds__(1024) void kF(
    const float* __restrict__ b1, const float* __restrict__ b2,
    const float* __restrict__ wsc, float* ws)
{
  const int b = blockIdx.x, t = threadIdx.x;
  const int w = t >> 6, lane = t & 63, lr = lane >> 3, lc = lane & 7;
  __shared__ __align__(16) float Apad[5120];
  __shared__ __align__(16) float Yl[4096];
  __shared__ __align__(16) float Pq[18432];
  __shared__ __align__(16) float Hpad[2560];
  __shared__ __align__(16) float Wsm[2048];
  __shared__ __align__(16) float Wsm2[2048];
  unsigned int* wsi = (unsigned int*)ws;

  if (t < 1024) {
    int ci = t >> 4, r9 = (t >> 3) & 1, c = t & 7;
    Apad[ci * 80 + r9 * 72 + c] = 0.f;
  }
  if (t < 512) {
    int ci = t >> 4, r9 = (t >> 3) & 1, c = t & 7;
    Hpad[ci * 80 + r9 * 72 + c] = 0.f;
  }

  {
    const int co4 = t & 15, p = t >> 4;
    const int py = p >> 3, px = p & 7;
    float4 a = ((const float4*)b1)[co4];
#pragma unroll
    for (int k = 0; k < 9; k++) {
      int dy = k / 3 - 1, dx = k % 3 - 1;
      int qy = py + dy, qx = px + dx;
      if ((unsigned)qy < 8u && (unsigned)qx < 8u) {
        int ik = qy * 8 + qx;
        float4 v = *(const float4*)(wsc + OFF_X1W + ((b * 64 + ik) * 9 + k) * 64 + co4 * 4);
        a.x += v.x; a.y += v.y; a.z += v.z; a.w += v.w;
      }
    }
    float av[4] = {a.x, a.y, a.z, a.w};
#pragma unroll
    for (int j = 0; j < 4; j++) {
      int co = co4 * 4 + j;
      Yl[co * 64 + p] = av[j];
      Apad[co * 80 + 8 + p] = fmaxf(av[j], 0.f);
    }
  }
  __syncthreads();
  if (t < 64) {
    unsigned int lo = 0, hi = 0;
#pragma unroll
    for (int ci = 0; ci < 32; ci++) lo |= (Yl[ci * 64 + t] > 0.f ? 1u : 0u) << ci;
#pragma unroll
    for (int ci = 0; ci < 32; ci++) hi |= (Yl[(32 + ci) * 64 + t] > 0.f ? 1u : 0u) << ci;
    wsi[OFF_MBIT + ((b * 3 + 0) * 64 + t) * 2]     = lo;
    wsi[OFF_MBIT + ((b * 3 + 0) * 64 + t) * 2 + 1] = hi;
  }

  float acc[4][8];
  for (int s = 0; s < 2; s++) {
    {
      const float2* src = (const float2*)(wsc + OFF_W1RT + s * 18432);
      float2* dst = (float2*)Pq;
#pragma unroll
      for (int z = 0; z < 9; z++) dst[z * 1024 + t] = src[z * 1024 + t];
    }
    __syncthreads();
    if (w < 8) {
#pragma unroll
      for (int j = 0; j < 4; j++)
#pragma unroll
        for (int px = 0; px < 8; px++) acc[j][px] = 0.f;
      conv3x3_tile(Pq, 32, 0, Apad, w * 8, 8, lr, lc, acc);
    } else {
      int tt = t - 512;
#pragma unroll
      for (int z = 0; z < 4; z++) Wsm[z * 512 + tt] = wsc[OFF_W2RT + s * 2048 + z * 512 + tt];
      if (s == 1) {
#pragma unroll
        for (int z = 0; z < 4; z++) Wsm2[z * 512 + tt] = wsc[OFF_WC2T + z * 512 + tt];
      }
    }
    __syncthreads();
    if (w < 8) store_tile(Pq + w * 2048, lr, lc, acc);
    __syncthreads();
    for (int e = t; e < 2048; e += 1024) {
      int rh = e >> 6, p = e & 63;
      float hv = 0.f;
#pragma unroll
      for (int ks = 0; ks < 8; ks++) hv += Pq[ks * 2048 + e];
      ws[OFF_N + (b * 2 + s) * 2048 + e] = hv > 0.f ? 1.f : 0.f;
      Hpad[rh * 80 + 8 + p] = fmaxf(hv, 0.f);
    }
    __syncthreads();
    if (w < 8) {
#pragma unroll
      for (int j = 0; j < 4; j++)
#pragma unroll
        for (int px = 0; px < 8; px++) acc[j][px] = 0.f;
      const int cohalf = w & 1, ks = w >> 1;
      conv1x1_tile(Wsm, 64, cohalf * 32, Hpad, ks * 8, 8, lr, lc, acc);
      store_tile(Pq + ks * 4096 + cohalf * 2048, lr, lc, acc);
    }
    __syncthreads();
    for (int e = t; e < 4096; e += 1024) {
      int co = e >> 6, p = e & 63;
      int pin = (co >> 5) * 2048 + (co & 31) * 64 + p;
      float d = 0.f;
#pragma unroll
      for (int ks = 0; ks < 4; ks++) d += Pq[ks * 4096 + pin];
      float ny = Yl[e] + d;
      Yl[e] = ny;
      Apad[co * 80 + 8 + p] = fmaxf(ny, 0.f);
    }
    __syncthreads();
    if (t < 64) {
      unsigned int lo = 0, hi = 0;
#pragma unroll
      for (int ci = 0; ci < 32; ci++) lo |= (Yl[ci * 64 + t] > 0.f ? 1u : 0u) << ci;
#pragma unroll
      for (int ci = 0; ci < 32; ci++) hi |= (Yl[(32 + ci) * 64 + t] > 0.f ? 1u : 0u) << ci;
      wsi[OFF_MBIT + ((b * 3 + 1 + s) * 64 + t) * 2]     = lo;
      wsi[OFF_MBIT + ((b * 3 + 1 + s) * 64 + t) * 2 + 1] = hi;
    }
  }

  if (w < 8) {
#pragma unroll
    for (int j = 0; j < 4; j++)
#pragma unroll
      for (int px = 0; px < 8; px++) acc[j][px] = 0.f;
    conv1x1_tile(Wsm2, 32, 0, Apad, w * 8, 8, lr, lc, acc);
    store_tile(Pq + w * 2048, lr, lc, acc);
  }
  __syncthreads();
  for (int e = t; e < 2048; e += 1024) {
    int o = e >> 6, p = e & 63;
    float yv = b2[o];
#pragma unroll
    for (int ks = 0; ks < 8; ks++) yv += Pq[ks * 2048 + e];
    ws[OFF_Y + b * 2048 + p * 32 + o] = yv;  // [b][tok][c]
  }
}

// ---------------- kHopG: wide hopfield -> g, one wave per (b,tok) ----------------
__global__ __launch_bounds__(64) void kHopG(const float* __restrict__ wsc,
                                            const float* __restrict__ pat,
                                            float* __restrict__ ws)
{
  const int b = blockIdx.x >> 6, tok = blockIdx.x & 63;
  const int lane = threadIdx.x;
  const float* yp = wsc + OFF_Y + b * 2048 + tok * 32;
  float4 ya[8];
#pragma unroll
  for (int r = 0; r < 8; r++) ya[r] = ((const float4*)yp)[r];

  float l[8];
#pragma unroll
  for (int j = 0; j < 8; j++) {
    const float4* pp = (const float4*)(pat + (j * 64 + lane) * 32);
    float lj = 0.f;
#pragma unroll
    for (int c4 = 0; c4 < 8; c4++) {
      float4 pv = pp[c4];
      lj = fmaf(ya[c4].x, pv.x, lj);
      lj = fmaf(ya[c4].y, pv.y, lj);
      lj = fmaf(ya[c4].z, pv.z, lj);
      lj = fmaf(ya[c4].w, pv.w, lj);
    }
    l[j] = lj * 0.17677669529663687f;
  }
  float mx = -1e30f;
#pragma unroll
  for (int j = 0; j < 8; j++) mx = fmaxf(mx, l[j]);
#pragma unroll
  for (int off = 32; off > 0; off >>= 1) mx = fmaxf(mx, __shfl_xor(mx, off, 64));
  float num[8]; float dsum = 0.f;
#pragma unroll
  for (int j = 0; j < 8; j++) { num[j] = __expf(l[j] - mx); dsum += num[j]; }
#pragma unroll
  for (int off = 32; off > 0; off >>= 1) dsum += __shfl_xor(dsum, off, 64);

  float q[32];
#pragma unroll
  for (int c = 0; c < 32; c++) q[c] = 0.f;
#pragma unroll
  for (int j = 0; j < 8; j++) {
    const float4* pp = (const float4*)(pat + (j * 64 + lane) * 32);
    float nj = num[j];
#pragma unroll
    for (int c4 = 0; c4 < 8; c4++) {
      float4 pv = pp[c4];
      q[c4 * 4 + 0] = fmaf(nj, pv.x, q[c4 * 4 + 0]);
      q[c4 * 4 + 1] = fmaf(nj, pv.y, q[c4 * 4 + 1]);
      q[c4 * 4 + 2] = fmaf(nj, pv.z, q[c4 * 4 + 2]);
      q[c4 * 4 + 3] = fmaf(nj, pv.w, q[c4 * 4 + 3]);
    }
  }
#pragma unroll
  for (int off = 32; off > 0; off >>= 1) {
#pragma unroll
    for (int c = 0; c < 32; c++) q[c] += __shfl_xor(q[c], off, 64);
  }
  if (lane == 0) {
    float invd = 1.f / dsum;
    float yy[32];
#pragma unroll
    for (int c4 = 0; c4 < 8; c4++) {
      yy[c4 * 4 + 0] = ya[c4].x; yy[c4 * 4 + 1] = ya[c4].y;
      yy[c4 * 4 + 2] = ya[c4].z; yy[c4 * 4 + 3] = ya[c4].w;
    }
    float* gp = ws + OFF_G + b * 2048 + tok * 32;
#pragma unroll
    for (int c4 = 0; c4 < 8; c4++)
      *(float4*)(gp + c4 * 4) = make_float4(
          2.f * (yy[c4 * 4 + 0] - q[c4 * 4 + 0] * invd),
          2.f * (yy[c4 * 4 + 1] - q[c4 * 4 + 1] * invd),
          2.f * (yy[c4 * 4 + 2] - q[c4 * 4 + 2] * invd),
          2.f * (yy[c4 * 4 + 3] - q[c4 * 4 + 3] * invd));
  }
}

// ---------------- kJ: paired tangents, 4 waves = 2 independent 2-wave pipes ----------------
__global__ __launch_bounds__(256) void kJ(const float* __restrict__ wsc, float* ws)
{
  const int bid = blockIdx.x;              // 512 blocks: (b, i)
  const int i = bid & 63, b = bid >> 6;
  const int t = threadIdx.x;
  const int type = t >> 7;                 // pair = tangent type
  const int tt = t & 127;                  // thread id within pair
  const int w = tt >> 6, p = tt & 63;      // wave-in-pair owns ci/co half w
  const int lr = p >> 3, lc = p & 7;
  const int py = p >> 3, px = p & 7, iy = i >> 3, ix = i & 7;
  __shared__ __align__(16) float UpA[10240];  // 2 x padded im2col / flat dT scratch
  __shared__ __align__(16) float PpA[8192];   // 2 x partials / V / out partials
  float* Up = UpA + type * 5120;
  float* Pp = PpA + type * 4096;
  const unsigned int* wsi = (const unsigned int*)wsc;

  float Tch[32];  // this wave's half of the tangent state at pixel p
  {
    int kh = iy - py + 1, kw = ix - px + 1;
    bool v0 = (unsigned)kh < 3u && (unsigned)kw < 3u;
    int kidx = v0 ? kh * 3 + kw : 0;
    const float4* s4 = (const float4*)(type
        ? (wsc + OFF_X1W + ((b * 64 + i) * 9 + kidx) * 64)
        : (wsc + OFF_WSUM + kidx * 64)) + w * 8;
#pragma unroll
    for (int c4 = 0; c4 < 8; c4++) {
      float4 tv = s4[c4];
      Tch[c4 * 4 + 0] = v0 ? tv.x : 0.f;
      Tch[c4 * 4 + 1] = v0 ? tv.y : 0.f;
      Tch[c4 * 4 + 2] = v0 ? tv.z : 0.f;
      Tch[c4 * 4 + 3] = v0 ? tv.w : 0.f;
    }
  }

  float accA[4][8];
  for (int s = 0; s < 2; s++) {
    if (s) __syncthreads();   // other wave's flat dT reads done before padded rebuild
    // masked padded build + pad-zero (own ci half only)
    unsigned int mw = wsi[OFF_MBIT + ((b * 3 + s) * 64 + p) * 2 + w];
#pragma unroll
    for (int c = 0; c < 32; c++)
      Up[(w * 32 + c) * 80 + 8 + p] = ((mw >> c) & 1u) ? Tch[c] : 0.f;
#pragma unroll
    for (int z = 0; z < 8; z++) {
      int e = z * 64 + p;
      int ci = w * 32 + (e >> 4);
      Up[ci * 80 + ((e >> 3) & 1) * 72 + (e & 7)] = 0.f;
    }
    // conv3x3 partial over own ci half -> 32 co
#pragma unroll
    for (int j = 0; j < 4; j++)
#pragma unroll
      for (int pq = 0; pq < 8; pq++) accA[j][pq] = 0.f;
    conv3x3_tile(wsc + OFF_W1RT + s * 18432, 32, 0, Up, w * 32, 32, lr, lc, accA);
    store_tile(Pp + w * 2048, lr, lc, accA);
    __syncthreads();
    // V = N * (partial0 + partial1), in place into Pp[0..2047]
    {
      float4* Pp4 = (float4*)Pp;
      const float4* Np4 = (const float4*)(wsc + OFF_N + (b * 2 + s) * 2048);
#pragma unroll
      for (int z = 0; z < 4; z++) {
        int e4 = z * 128 + tt;
        float4 a = Pp4[e4], bq = Pp4[512 + e4], nv = Np4[e4];
        Pp4[e4] = make_float4((a.x + bq.x) * nv.x, (a.y + bq.y) * nv.y,
                              (a.z + bq.z) * nv.z, (a.w + bq.w) * nv.w);
      }
    }
    __syncthreads();
    // dT(own co half) = W2^T V, K=32 full; then Tch += dT
#pragma unroll
    for (int j = 0; j < 4; j++)
#pragma unroll
      for (int pq = 0; pq < 8; pq++) accA[j][pq] = 0.f;
    conv1x1_flat(wsc + OFF_W2RT + s * 2048, 64, w * 32, Pp, 0, 32, lr, lc, accA);
    store_tile(Up + w * 2048, lr, lc, accA);   // own flat region
#pragma unroll
    for (int c = 0; c < 32; c++) Tch[c] += Up[w * 2048 + c * 64 + p];
  }
  __syncthreads();
  // final 1x1 with M2 mask: masked flat build (own half) + K-split conv
  {
    unsigned int mw = wsi[OFF_MBIT + ((b * 3 + 2) * 64 + p) * 2 + w];
#pragma unroll
    for (int c = 0; c < 32; c++)
      Up[(w * 32 + c) * 64 + p] = ((mw >> c) & 1u) ? Tch[c] : 0.f;
#pragma unroll
    for (int j = 0; j < 4; j++)
#pragma unroll
      for (int pq = 0; pq < 8; pq++) accA[j][pq] = 0.f;
    conv1x1_flat(wsc + OFF_WC2T, 32, 0, Up, w * 32, 32, lr, lc, accA);
    store_tile(Pp + w * 2048, lr, lc, accA);
  }
  __syncthreads();

  if (type == 0) {
    if (w == 0) {
      // e[m=p] = sum_o g[b][p][o] * out[o][p]
      const float* gp = wsc + OFF_G + b * 2048 + p * 32;
      float e = 0.f;
#pragma unroll
      for (int o4 = 0; o4 < 8; o4++) {
        float4 gv = *(const float4*)(gp + o4 * 4);
        int o = o4 * 4;
        e = fmaf(gv.x, Pp[(o + 0) * 64 + p] + Pp[2048 + (o + 0) * 64 + p], e);
        e = fmaf(gv.y, Pp[(o + 1) * 64 + p] + Pp[2048 + (o + 1) * 64 + p], e);
        e = fmaf(gv.z, Pp[(o + 2) * 64 + p] + Pp[2048 + (o + 2) * 64 + p], e);
        e = fmaf(gv.w, Pp[(o + 3) * 64 + p] + Pp[2048 + (o + 3) * 64 + p], e);
      }
      float bv = e; int bi = p;
#pragma unroll
      for (int off = 1; off < 64; off <<= 1) {
        float ov = __shfl_xor(bv, off, 64);
        int oi = __shfl_xor(bi, off, 64);
        if (ov < bv || (ov == bv && oi < bi)) { bv = ov; bi = oi; }
      }
      if (p == 0) ((int*)(ws + OFF_IDX))[b * 64 + i] = bi;
    }
  } else {
    // T[b][i][m][o], 512 float4 over the pair's 128 threads
    float* Tp = ws + OFF_T + (b * 64 + i) * 2048;
#pragma unroll
    for (int z = 0; z < 4; z++) {
      int e4 = z * 128 + tt;
      int m = e4 >> 3, o0 = (e4 & 7) * 4;
      *(float4*)(Tp + e4 * 4) = make_float4(
          Pp[(o0 + 0) * 64 + m] + Pp[2048 + (o0 + 0) * 64 + m],
          Pp[(o0 + 1) * 64 + m] + Pp[2048 + (o0 + 1) * 64 + m],
          Pp[(o0 + 2) * 64 + m] + Pp[2048 + (o0 + 2) * 64 + m],
          Pp[(o0 + 3) * 64 + m] + Pp[2048 + (o0 + 3) * 64 + m]);
    }
  }
}

// ---------------- kQ: routed gather + hopfield -> out ----------------
__global__ __launch_bounds__(64) void kQ(const float* __restrict__ wsc,
                                         const float* __restrict__ pat,
                                         float* __restrict__ outp)
{
  const int b = blockIdx.x >> 6, tok = blockIdx.x & 63;
  const int lane = threadIdx.x;
  const int sidx = ((const int*)(wsc + OFF_IDX))[b * 64 + lane];
  const bool sel = (sidx == tok);
  float ym[32];
  const float4* Tp = (const float4*)(wsc + OFF_T + ((b * 64 + lane) * 64 + tok) * 32);
#pragma unroll
  for (int c4 = 0; c4 < 8; c4++) {
    float4 tv = Tp[c4];
    ym[c4 * 4 + 0] = sel ? tv.x : 0.f;
    ym[c4 * 4 + 1] = sel ? tv.y : 0.f;
    ym[c4 * 4 + 2] = sel ? tv.z : 0.f;
    ym[c4 * 4 + 3] = sel ? tv.w : 0.f;
  }
#pragma unroll
  for (int off = 1; off < 64; off <<= 1) {
#pragma unroll
    for (int c = 0; c < 32; c++) ym[c] += __shfl_xor(ym[c], off, 64);
  }
  float l[8];
#pragma unroll
  for (int j = 0; j < 8; j++) {
    const float4* pp = (const float4*)(pat + (j * 64 + lane) * 32);
    float lj = 0.f;
#pragma unroll
    for (int c4 = 0; c4 < 8; c4++) {
      float4 pv = pp[c4];
      lj = fmaf(ym[c4 * 4 + 0], pv.x, lj);
      lj = fmaf(ym[c4 * 4 + 1], pv.y, lj);
      lj = fmaf(ym[c4 * 4 + 2], pv.z, lj);
      lj = fmaf(ym[c4 * 4 + 3], pv.w, lj);
    }
    l[j] = lj * 0.17677669529663687f;
  }
  float mx = -1e30f;
#pragma unroll
  for (int j = 0; j < 8; j++) mx = fmaxf(mx, l[j]);
#pragma unroll
  for (int off = 32; off > 0; off >>= 1) mx = fmaxf(mx, __shfl_xor(mx, off, 64));
  float num[8]; float dsum = 0.f;
#pragma unroll
  for (int j = 0; j < 8; j++) { num[j] = __expf(l[j] - mx); dsum += num[j]; }
#pragma unroll
  for (int off = 32; off > 0; off >>= 1) dsum += __shfl_xor(dsum, off, 64);
  float q[32];
#pragma unroll
  for (int c = 0; c < 32; c++) q[c] = 0.f;
#pragma unroll
  for (int j = 0; j < 8; j++) {
    const float4* pp = (const float4*)(pat + (j * 64 + lane) * 32);
    float nj = num[j];
#pragma unroll
    for (int c4 = 0; c4 < 8; c4++) {
      float4 pv = pp[c4];
      q[c4 * 4 + 0] = fmaf(nj, pv.x, q[c4 * 4 + 0]);
      q[c4 * 4 + 1] = fmaf(nj, pv.y, q[c4 * 4 + 1]);
      q[c4 * 4 + 2] = fmaf(nj, pv.z, q[c4 * 4 + 2]);
      q[c4 * 4 + 3] = fmaf(nj, pv.w, q[c4 * 4 + 3]);
    }
  }
#pragma unroll
  for (int off = 32; off > 0; off >>= 1) {
#pragma unroll
    for (int c = 0; c < 32; c++) q[c] += __shfl_xor(q[c], off, 64);
  }
  if (lane == 0) {
    float invd = 1.f / dsum;
#pragma unroll
    for (int c = 0; c < 32; c++)
      outp[b * 2048 + c * 64 + tok] = q[c] * invd;
  }
}

extern "C" void kernel_launch(void* const* d_in, const int* in_sizes, int n_in,
                              void* d_out, int out_size, void* d_ws, size_t ws_size,
                              hipStream_t stream) {
  (void)in_sizes; (void)n_in; (void)out_size; (void)ws_size;
  const float* x    = (const float*)d_in[0];
  const float* w1   = (const float*)d_in[1];
  const float* b1   = (const float*)d_in[2];
  const float* r0w1 = (const float*)d_in[3];
  const float* r0w2 = (const float*)d_in[4];
  const float* r1w1 = (const float*)d_in[5];
  const float* r1w2 = (const float*)d_in[6];
  const float* w2   = (const float*)d_in[7];
  const float* b2   = (const float*)d_in[8];
  const float* pat  = (const float*)d_in[9];
  float* ws  = (float*)d_ws;
  float* out = (float*)d_out;

  kP<<<80, 256, 0, stream>>>(x, w1, r0w1, r0w2, r1w1, r1w2, w2, ws);
  kF<<<8, 1024, 0, stream>>>(b1, b2, ws, ws);
  kHopG<<<512, 64, 0, stream>>>(ws, pat, ws);
  kJ<<<512, 256, 0, stream>>>(ws, ws);
  kQ<<<512, 64, 0, stream>>>(ws, pat, out);
}